// Round 1
// baseline (537.549 us; speedup 1.0000x reference)
//
#include <hip/hip_runtime.h>
#include <math.h>

// out[i, j, k] = K[j, k] * a[i, k],  K[j, m] = exp(-GAMMA * ||a_j - b_m||^2)
// N = 1024, M = D = 128. Softmax over a length-1 axis == 1, so
// rotation_params/entangle_params are mathematically dead.
// Write-bandwidth bound: 512 MiB output.

#define GAMMA_F 1.0f
#define N_ROWS 1024
#define DIM    128

// ---------------------------------------------------------------------------
// Kernel 1: K[j, m] = exp(-||a_j - b_m||^2).  grid = 1024 blocks, 128 threads.
// a-row staged in LDS (float4), each thread streams its own b-row (L2-hot).
// ---------------------------------------------------------------------------
__global__ __launch_bounds__(DIM) void compute_K_kernel(
    const float* __restrict__ a,
    const float* __restrict__ b,
    float* __restrict__ K)
{
    __shared__ float4 a_sh[DIM / 4];
    const int j = blockIdx.x;
    const int m = threadIdx.x;

    if (m < DIM / 4) {
        a_sh[m] = reinterpret_cast<const float4*>(a + (size_t)j * DIM)[m];
    }
    __syncthreads();

    const float4* b4 = reinterpret_cast<const float4*>(b + (size_t)m * DIM);
    float acc = 0.0f;
#pragma unroll 8
    for (int d = 0; d < DIM / 4; ++d) {
        const float4 av = a_sh[d];
        const float4 bv = b4[d];
        const float dx = av.x - bv.x;
        const float dy = av.y - bv.y;
        const float dz = av.z - bv.z;
        const float dw = av.w - bv.w;
        acc = fmaf(dx, dx, acc);
        acc = fmaf(dy, dy, acc);
        acc = fmaf(dz, dz, acc);
        acc = fmaf(dw, dw, acc);
    }
    K[(size_t)j * DIM + m] = expf(-GAMMA_F * acc);
}

// ---------------------------------------------------------------------------
// Kernel 2: out4[v] = a4[i*32 + k4] * K4[j*32 + k4]  (elementwise float4)
//   v = flat float4 index; k4 = v & 31; row = v >> 5; j = row & 1023; i = row >> 10
// One float4 (16 B) store per lane — the coalescing sweet spot.
// ---------------------------------------------------------------------------
__global__ __launch_bounds__(256) void bcast_mul_kernel(
    const float4* __restrict__ a4,
    const float4* __restrict__ K4,
    float4* __restrict__ out4,
    unsigned n_vec)
{
    const unsigned v = blockIdx.x * 256u + threadIdx.x;
    if (v >= n_vec) return;

    const unsigned k4  = v & 31u;         // 32 float4 per 128-float row
    const unsigned row = v >> 5;          // (i, j) pair index
    const unsigned j   = row & 1023u;
    const unsigned i   = row >> 10;

    const float4 av = a4[i * 32u + k4];
    const float4 kv = K4[j * 32u + k4];

    float4 o;
    o.x = av.x * kv.x;
    o.y = av.y * kv.y;
    o.z = av.z * kv.z;
    o.w = av.w * kv.w;
    out4[v] = o;
}

extern "C" void kernel_launch(void* const* d_in, const int* in_sizes, int n_in,
                              void* d_out, int out_size, void* d_ws, size_t ws_size,
                              hipStream_t stream)
{
    const float* a = reinterpret_cast<const float*>(d_in[0]);   // [1024, 128]
    const float* b = reinterpret_cast<const float*>(d_in[1]);   // [128, 128]
    // d_in[2], d_in[3] (rotation/entangle params) are dead: softmax over a
    // length-1 axis is identically 1, so attn_weights == a.

    float* K = reinterpret_cast<float*>(d_ws);                  // [1024, 128] scratch (512 KB)

    compute_K_kernel<<<N_ROWS, DIM, 0, stream>>>(a, b, K);

    const unsigned n_vec = (unsigned)(out_size / 4);            // 33,554,432 float4
    const unsigned blocks = (n_vec + 255u) / 256u;              // 131,072
    bcast_mul_kernel<<<blocks, 256, 0, stream>>>(
        reinterpret_cast<const float4*>(a),
        reinterpret_cast<const float4*>(K),
        reinterpret_cast<float4*>(d_out),
        n_vec);
}